// Round 14
// baseline (1109.513 us; speedup 1.0000x reference)
//
#include <hip/hip_runtime.h>

#define NPIX 4096
#define CHN  64

typedef __attribute__((ext_vector_type(8))) short short8;
typedef __attribute__((ext_vector_type(8))) unsigned short ushort8;
typedef __attribute__((ext_vector_type(4))) unsigned short ushort4v;
typedef __attribute__((ext_vector_type(4))) float f32x4;

__device__ __forceinline__ float lrelu_(float x){ return x >= 0.f ? x : 0.01f*x; }

__device__ __forceinline__ unsigned short f2bf(float x){
  union { float f; unsigned u; } v; v.f = x;
  unsigned r = v.u + 0x7FFF + ((v.u >> 16) & 1);
  return (unsigned short)(r >> 16);
}
__device__ __forceinline__ float bf2f(unsigned short h){
  union { unsigned u; float f; } v; v.u = ((unsigned)h) << 16;
  return v.f;
}

// ---------------- fused positional table + weight transpose ----------------
// idx < 131072: pos[32][4096]; else wt (q 49152 | fk/ck/fv/cv 81920 ea | conv 4800)
__global__ void poswtr_kernel(const float* __restrict__ qw, const float* __restrict__ fkw,
                              const float* __restrict__ ckw, const float* __restrict__ fvw,
                              const float* __restrict__ cvw, const float* __restrict__ convw,
                              float* __restrict__ pos, float* __restrict__ wt){
  int gid = blockIdx.x*256 + threadIdx.x;
  if (gid < 131072){
    int c = gid >> 12;
    int n = gid & (NPIX-1);
    int bcoord = (c < 16) ? (n >> 6) : (n & 63);
    int a = (c < 16) ? c : (c - 16);
    int flat = a*64 + bcoord;
    int p = flat >> 4;
    int j = flat & 15;
    float val = 0.f;
    if (p != 0){
      float ex = (float)(j & ~1) * (1.f/16.f);
      float w = powf(10000.f, -ex);
      float ang = (float)p * w;
      val = (j & 1) ? cosf(ang) : sinf(ang);
    }
    pos[gid] = val;
    return;
  }
  int idx = gid - 131072;
  if (idx >= 381632) return;
  if (idx < 49152){
    int l = idx / 6144, r = idx % 6144, i = r >> 6, o = r & 63;
    wt[idx] = qw[(l*64 + o)*96 + i];
  } else if (idx < 376832){
    int e = idx - 49152;
    int mat = e / 81920, r = e % 81920;
    int l = r / 10240, rr = r % 10240, i = rr >> 6, o = rr & 63;
    const float* src = (mat==0) ? fkw : (mat==1) ? ckw : (mat==2) ? fvw : cvw;
    wt[idx] = src[(l*64 + o)*160 + i];
  } else {
    int e = idx - 376832;
    int o = e & 63, tap = e >> 6;
    int ci = tap / 25, r = tap % 25;
    wt[idx] = convw[(o*3 + ci)*25 + r];
  }
}

// ---------------- masked causal 5x5 conv (input layer) ----------------
__global__ __launch_bounds__(256) void conv_in_kernel(const float* __restrict__ x,
                                                      const float* __restrict__ cwt,
                                                      const float* __restrict__ cb,
                                                      float* __restrict__ out){
  int t = threadIdx.x;
  int o = t & 63;
  int sub = t >> 6;
  int bid = blockIdx.x;
  int b = bid >> 10;
  int n = ((bid & 1023) << 2) + sub;
  int y = n >> 6, xx = n & 63;
  float acc = cb[o];
  #pragma unroll
  for (int ci=0; ci<3; ++ci){
    const float* xp = x + ((b*3+ci)<<12);
    #pragma unroll
    for (int ky=0; ky<3; ++ky){
      int yy = y + ky - 2;
      if (yy < 0) continue;
      int nk = (ky==2) ? 2 : 5;
      #pragma unroll
      for (int kx=0; kx<5; ++kx){
        if (kx >= nk) break;
        int xc = xx + kx - 2;
        if (xc < 0 || xc > 63) continue;
        acc += xp[(yy<<6) + xc] * cwt[(ci*25 + ky*5 + kx)*64 + o];
      }
    }
  }
  out[(b*CHN+o)*NPIX + n] = acc;
}

// ---------------- batch-norm stats (conv path only) ----------------
__global__ __launch_bounds__(1024) void bn_stats_kernel(const float* __restrict__ xin,
                                                        float* __restrict__ stats){
  int c = blockIdx.x;
  int t = threadIdx.x;
  float s = 0.f, ss = 0.f;
  #pragma unroll
  for (int it=0; it<8; ++it){
    int idx = t + it*1024;
    float v = xin[(((idx>>12))*CHN + c)*NPIX + (idx & (NPIX-1))];
    s += v; ss += v*v;
  }
  #pragma unroll
  for (int o=1; o<64; o<<=1){ s += __shfl_xor(s,o); ss += __shfl_xor(ss,o); }
  __shared__ float ps[16], pq[16];
  if ((t & 63) == 0){ ps[t>>6] = s; pq[t>>6] = ss; }
  __syncthreads();
  if (t == 0){
    float S=0.f, Q=0.f;
    #pragma unroll
    for (int i=0;i<16;++i){ S += ps[i]; Q += pq[i]; }
    float mu = S*(1.f/8192.f);
    float var = Q*(1.f/8192.f) - mu*mu;
    var = fmaxf(var, 0.f);
    stats[c*2]   = mu;
    stats[c*2+1] = rsqrtf(var + 1e-5f);
  }
}

// ---------------- BN apply + LeakyReLU (conv path) ----------------
__global__ void bn_apply_kernel(const float* __restrict__ xin, const float* __restrict__ stats,
                                const float* __restrict__ g, const float* __restrict__ bb,
                                float* __restrict__ hout){
  int idx = blockIdx.x*256 + threadIdx.x;
  int e = idx << 2;
  int c = (e >> 12) & 63;
  float mu = stats[c*2], rstd = stats[c*2+1];
  float gain = g[c]*rstd;
  float beta = bb[c] - gain*mu;
  float4 v = *(const float4*)(xin + e);
  float4 r;
  r.x = lrelu_(gain*v.x + beta);
  r.y = lrelu_(gain*v.y + beta);
  r.z = lrelu_(gain*v.z + beta);
  r.w = lrelu_(gain*v.w + beta);
  *(float4*)(hout + e) = r;
}

// ---------------- five 1x1 convs, section-split ----------------
// grid 1536 = sec(3) x b(2) x tile(256 of 16 px); block 256 = 4 waves x 4 px.
__global__ __launch_bounds__(256) void cv1_kernel(
    const float* __restrict__ hbuf, const float* __restrict__ pos,
    const float* __restrict__ kold, const float* __restrict__ vold,
    const float* __restrict__ qwt,
    const float* __restrict__ fkwt, const float* __restrict__ ckwt,
    const float* __restrict__ fvwt, const float* __restrict__ cvwt,
    const float* __restrict__ qbi,  const float* __restrict__ fkb,
    const float* __restrict__ ckb,  const float* __restrict__ fvb,
    const float* __restrict__ cvb,
    unsigned short* __restrict__ qh, unsigned short* __restrict__ ql,
    float* __restrict__ knew, unsigned short* __restrict__ khn, unsigned short* __restrict__ kln,
    float* __restrict__ vnew, unsigned short* __restrict__ vhTn, unsigned short* __restrict__ vlTn)
{
  int t = threadIdx.x;
  int o  = t & 63;
  int wv = t >> 6;                      // 0..3
  int sec  = blockIdx.x >> 9;           // 0,1,2
  int bid  = blockIdx.x & 511;
  int b    = bid >> 8;
  int tile = bid & 255;
  int n0 = tile*16 + wv*4;

  const float* hb = hbuf + b*CHN*NPIX + n0;
  const float* pb = pos + n0;

  auto load4 = [&](const float* p, float* dst){
    float4 a = *(const float4*)p;
    dst[0]=a.x; dst[1]=a.y; dst[2]=a.z; dst[3]=a.w;
  };

  float x[4];
  long obase = (long)(b*CHN+o)*NPIX + n0;
  size_t nbase = ((size_t)b*NPIX + n0)*64 + o;

  if (sec == 0){
    float aq[4];
    float bias = qbi[o];
    #pragma unroll
    for (int j=0;j<4;++j) aq[j]=bias;
    #pragma unroll 4
    for (int i=0;i<64;++i){
      load4(hb + i*NPIX, x);
      float w = qwt[i*64 + o];
      #pragma unroll
      for (int j=0;j<4;++j) aq[j] += w*x[j];
    }
    #pragma unroll 4
    for (int i=0;i<32;++i){
      load4(pb + i*NPIX, x);
      float w = qwt[(64+i)*64 + o];
      #pragma unroll
      for (int j=0;j<4;++j) aq[j] += w*x[j];
    }
    const float QS = 0.125f;            // expf-domain softmax
    #pragma unroll
    for (int j=0;j<4;++j){
      float v = lrelu_(aq[j]) * QS;
      unsigned short hb16 = f2bf(v);
      qh[nbase + (size_t)j*64] = hb16;
      ql[nbase + (size_t)j*64] = f2bf(v - bf2f(hb16));
    }
  } else if (sec == 1){
    const float* kb = kold + b*CHN*NPIX + n0;
    float af[4], ac[4];
    float bf = fkb[o], bc = ckb[o];
    #pragma unroll
    for (int j=0;j<4;++j){ af[j]=bf; ac[j]=bc; }
    #pragma unroll 4
    for (int i=0;i<64;++i){
      load4(hb + i*NPIX, x);
      float wf = fkwt[i*64+o], wc = ckwt[i*64+o];
      #pragma unroll
      for (int j=0;j<4;++j){ af[j] += wf*x[j]; ac[j] += wc*x[j]; }
    }
    #pragma unroll 4
    for (int i=0;i<32;++i){
      load4(pb + i*NPIX, x);
      float wf = fkwt[(64+i)*64+o], wc = ckwt[(64+i)*64+o];
      #pragma unroll
      for (int j=0;j<4;++j){ af[j] += wf*x[j]; ac[j] += wc*x[j]; }
    }
    #pragma unroll 4
    for (int i=0;i<64;++i){
      load4(kb + i*NPIX, x);
      float wf = fkwt[(96+i)*64+o], wc = ckwt[(96+i)*64+o];
      #pragma unroll
      for (int j=0;j<4;++j){ af[j] += wf*x[j]; ac[j] += wc*x[j]; }
    }
    float kv[4];
    load4(kb + o*NPIX, kv);
    #pragma unroll
    for (int j=0;j<4;++j){
      float fk = 1.f/(1.f+__expf(-af[j]));
      float kn = fk*kv[j] + lrelu_(ac[j]);
      knew[obase+j] = kn;
      unsigned short hb16 = f2bf(kn);
      khn[nbase + (size_t)j*64] = hb16;
      kln[nbase + (size_t)j*64] = f2bf(kn - bf2f(hb16));
    }
  } else {
    const float* vb = vold + b*CHN*NPIX + n0;
    float af[4], ac[4];
    float bf = fvb[o], bc = cvb[o];
    #pragma unroll
    for (int j=0;j<4;++j){ af[j]=bf; ac[j]=bc; }
    #pragma unroll 4
    for (int i=0;i<64;++i){
      load4(hb + i*NPIX, x);
      float wf = fvwt[i*64+o], wc = cvwt[i*64+o];
      #pragma unroll
      for (int j=0;j<4;++j){ af[j] += wf*x[j]; ac[j] += wc*x[j]; }
    }
    #pragma unroll 4
    for (int i=0;i<32;++i){
      load4(pb + i*NPIX, x);
      float wf = fvwt[(64+i)*64+o], wc = cvwt[(64+i)*64+o];
      #pragma unroll
      for (int j=0;j<4;++j){ af[j] += wf*x[j]; ac[j] += wc*x[j]; }
    }
    #pragma unroll 4
    for (int i=0;i<64;++i){
      load4(vb + i*NPIX, x);
      float wf = fvwt[(96+i)*64+o], wc = cvwt[(96+i)*64+o];
      #pragma unroll
      for (int j=0;j<4;++j){ af[j] += wf*x[j]; ac[j] += wc*x[j]; }
    }
    float vv[4];
    load4(vb + o*NPIX, vv);
    ushort4v vph, vpl;
    #pragma unroll
    for (int j=0;j<4;++j){
      float fv = 1.f/(1.f+__expf(-af[j]));
      float vn = fv*vv[j] + lrelu_(ac[j]);
      vnew[obase+j] = vn;
      unsigned short hb16 = f2bf(vn);
      vph[j] = hb16;
      vpl[j] = f2bf(vn - bf2f(hb16));
    }
    *(ushort4v*)(vhTn + ((size_t)(b*CHN+o))*NPIX + n0) = vph;
    *(ushort4v*)(vlTn + ((size_t)(b*CHN+o))*NPIX + n0) = vpl;
  }
}

// ---------------- MFMA flash attention (16x16x32, 640 blocks) ----
__global__ __launch_bounds__(128) void attn_mfma(
    const unsigned short* __restrict__ qhg, const unsigned short* __restrict__ qlg,
    const unsigned short* __restrict__ khg, const unsigned short* __restrict__ klg,
    const unsigned short* __restrict__ vhg, const unsigned short* __restrict__ vlg,
    float* __restrict__ part)
{
  int bid = 639 - (int)blockIdx.x;           // longest bands dispatched first
  int b = 0, id = bid;
  if (id >= 320){ b = 1; id -= 320; }
  int pidx = bid;
  int rem = id, k = 0;
  while (rem >= 32*(k+1)){ rem -= 32*(k+1); ++k; }
  int rt    = 32*k + rem/(k+1);
  int chunk = rem - (rem/(k+1))*(k+1);

  int C0  = chunk << 10;                      // 1024*chunk
  int end = min(C0 + 1024, rt*32 + 32);
  int nt  = (end - C0 + 63) >> 6;

  int t = threadIdx.x;
  int w = t >> 6;
  int l = t & 63;
  int r = l & 15;
  int g = l >> 4;
  int n_g = rt*32 + w*16 + r;                 // this lane's q-row

  __shared__ __align__(16) char KH[8192], KL[8192];
  __shared__ __align__(16) char VH[8192], VL[8192];
  __shared__ __align__(16) char PH[2][2048], PL[2][2048];

  const unsigned short* qhp = qhg + (size_t)b*NPIX*64;
  const unsigned short* qlp = qlg + (size_t)b*NPIX*64;
  const unsigned short* khp = khg + (size_t)b*NPIX*64;
  const unsigned short* klp = klg + (size_t)b*NPIX*64;
  const unsigned short* vhp = vhg + (size_t)b*CHN*NPIX;
  const unsigned short* vlp = vlg + (size_t)b*CHN*NPIX;

  short8 qh0 = *(const short8*)(qhp + (size_t)n_g*64 + 8*g);
  short8 qh1 = *(const short8*)(qhp + (size_t)n_g*64 + 8*g + 32);
  short8 ql0 = *(const short8*)(qlp + (size_t)n_g*64 + 8*g);
  short8 ql1 = *(const short8*)(qlp + (size_t)n_g*64 + 8*g + 32);

  int srow[4], scc8[4], soff[4];
  #pragma unroll
  for (int p=0; p<4; ++p){
    int slot = t + (p<<7);
    int row = slot >> 3, cc = slot & 7;
    srow[p] = row; scc8[p] = cc*8;
    soff[p] = row*128 + ((cc ^ (row & 7)) << 4);
  }

  ushort8 rkh[4], rkl[4], rvh[4], rvl[4];
  auto issue = [&](int m0){
    #pragma unroll
    for (int p=0; p<4; ++p){
      rkh[p] = *(const ushort8*)(khp + (size_t)(m0+srow[p])*64 + scc8[p]);
      rkl[p] = *(const ushort8*)(klp + (size_t)(m0+srow[p])*64 + scc8[p]);
      rvh[p] = *(const ushort8*)(vhp + (size_t)srow[p]*NPIX + m0 + scc8[p]);
      rvl[p] = *(const ushort8*)(vlp + (size_t)srow[p]*NPIX + m0 + scc8[p]);
    }
  };

  f32x4 zero4 = {0.f,0.f,0.f,0.f};
  f32x4 oacc[4];
  #pragma unroll
  for (int vf=0; vf<4; ++vf) oacc[vf] = zero4;
  float m_run = -1e30f, l_run = 0.f;

  int nmax_w = rt*32 + w*16 + 15;

  issue(C0);
  for (int ti=0; ti<nt; ++ti){
    int m0 = C0 + (ti<<6);
    __syncthreads();
    #pragma unroll
    for (int p=0; p<4; ++p){
      *(ushort8*)(KH + soff[p]) = rkh[p];
      *(ushort8*)(KL + soff[p]) = rkl[p];
      *(ushort8*)(VH + soff[p]) = rvh[p];
      *(ushort8*)(VL + soff[p]) = rvl[p];
    }
    __syncthreads();
    if (ti+1 < nt) issue(m0 + 64);

    if (m0 <= nmax_w){
      f32x4 sf[4];
      #pragma unroll
      for (int mf=0; mf<4; ++mf) sf[mf] = zero4;
      #pragma unroll
      for (int kc=0; kc<2; ++kc){
        short8 qfh = kc ? qh1 : qh0;
        short8 qfl = kc ? ql1 : ql0;
        int ch = ((g + 4*kc) ^ (r & 7)) << 4;
        #pragma unroll
        for (int mf=0; mf<4; ++mf){
          int ro = (16*mf + r)*128;
          short8 ah = *(const short8*)(KH + ro + ch);
          short8 al = *(const short8*)(KL + ro + ch);
          sf[mf] = __builtin_amdgcn_mfma_f32_16x16x32_bf16(ah, qfh, sf[mf], 0,0,0);
          sf[mf] = __builtin_amdgcn_mfma_f32_16x16x32_bf16(al, qfh, sf[mf], 0,0,0);
          sf[mf] = __builtin_amdgcn_mfma_f32_16x16x32_bf16(ah, qfl, sf[mf], 0,0,0);
        }
      }
      float pv[16];
      float mx = -1e30f;
      #pragma unroll
      for (int mf=0; mf<4; ++mf){
        #pragma unroll
        for (int q2=0; q2<4; ++q2){
          int mg = m0 + 16*mf + 4*g + q2;
          float s = sf[mf][q2];
          s = (mg <= n_g) ? s : -1e30f;
          pv[mf*4+q2] = s;
          mx = fmaxf(mx, s);
        }
      }
      mx = fmaxf(mx, __shfl_xor(mx, 16));
      mx = fmaxf(mx, __shfl_xor(mx, 32));
      float m_new = fmaxf(m_run, mx);
      float alpha = __expf(m_run - m_new);
      float ps = 0.f;
      #pragma unroll
      for (int i=0; i<16; ++i){ pv[i] = __expf(pv[i] - m_new); ps += pv[i]; }
      ps += __shfl_xor(ps, 16);
      ps += __shfl_xor(ps, 32);
      l_run = l_run*alpha + ps;
      m_run = m_new;

      #pragma unroll
      for (int mf=0; mf<4; ++mf){
        unsigned short h_[4], l_[4];
        #pragma unroll
        for (int q2=0; q2<4; ++q2){
          float xv = pv[mf*4+q2];
          h_[q2] = f2bf(xv);
          l_[q2] = f2bf(xv - bf2f(h_[q2]));
        }
        int addr = r*128 + ((((g>>1) + 2*mf) ^ (r & 7)) << 4) + ((g&1)<<3);
        uint2 wh = make_uint2((unsigned)h_[0] | ((unsigned)h_[1]<<16),
                              (unsigned)h_[2] | ((unsigned)h_[3]<<16));
        uint2 wl = make_uint2((unsigned)l_[0] | ((unsigned)l_[1]<<16),
                              (unsigned)l_[2] | ((unsigned)l_[3]<<16));
        *(uint2*)(PH[w] + addr) = wh;
        *(uint2*)(PL[w] + addr) = wl;
      }
      #pragma unroll
      for (int vf=0; vf<4; ++vf) oacc[vf] *= alpha;

      #pragma unroll
      for (int kc=0; kc<2; ++kc){
        int ch = ((g + 4*kc) ^ (r & 7)) << 4;
        short8 pfh = *(const short8*)(PH[w] + r*128 + ch);
        short8 pfl = *(const short8*)(PL[w] + r*128 + ch);
        #pragma unroll
        for (int vf=0; vf<4; ++vf){
          int ro = (16*vf + r)*128;
          short8 ah = *(const short8*)(VH + ro + ch);
          short8 al = *(const short8*)(VL + ro + ch);
          oacc[vf] = __builtin_amdgcn_mfma_f32_16x16x32_bf16(ah, pfh, oacc[vf], 0,0,0);
          oacc[vf] = __builtin_amdgcn_mfma_f32_16x16x32_bf16(al, pfh, oacc[vf], 0,0,0);
          oacc[vf] = __builtin_amdgcn_mfma_f32_16x16x32_bf16(ah, pfl, oacc[vf], 0,0,0);
        }
      }
    }
  }

  float* pacc = part + (size_t)pidx * 2112;
  int nl = w*16 + r;
  #pragma unroll
  for (int vf=0; vf<4; ++vf)
    *(f32x4*)(pacc + nl*64 + 16*vf + 4*g) = oacc[vf];
  if (g == 0){
    pacc[2048 + nl*2]   = m_run;
    pacc[2048 + nl*2+1] = l_run;
  }
}

// ---------------- attention phase 2: combine + FUSED batch-norm + lrelu -> h ----
// grid 256 (all co-resident). Release/acquire counter sync; deterministic stats.
__global__ __launch_bounds__(256) void attn_combine2(const float* __restrict__ part,
                                                     float* __restrict__ hout,
                                                     float* __restrict__ psum,
                                                     float* __restrict__ psq,
                                                     int* __restrict__ ctr,
                                                     const float* __restrict__ g,
                                                     const float* __restrict__ bb){
  int bid = blockIdx.x;               // b*128 + rt
  int b = bid >> 7, rt = bid & 127;
  int k = rt >> 5;
  int nch = k + 1;                    // <= 4
  int base = b*320 + 16*k*(k+1) + (rt - 32*k)*nch;

  int t = threadIdx.x;
  int nl = t & 31, vq = t >> 5;       // 32 rows x 8 vd-octets

  float M = -1e30f;
  #pragma unroll
  for (int c=0; c<4; ++c)
    if (c < nch) M = fmaxf(M, part[(size_t)(base+c)*2112 + 2048 + nl*2]);

  float L = 0.f;
  float val[8];
  #pragma unroll
  for (int jj=0; jj<8; ++jj) val[jj] = 0.f;
  #pragma unroll
  for (int c=0; c<4; ++c){
    if (c < nch){
      const float* pa = part + (size_t)(base+c)*2112;
      float wgt = __expf(pa[2048 + nl*2] - M);
      L += pa[2048 + nl*2 + 1] * wgt;
      #pragma unroll
      for (int jj=0; jj<8; ++jj) val[jj] += wgt * pa[nl*64 + vq*8 + jj];
    }
  }
  float invL = 1.f / L;
  float s[8], q[8];
  #pragma unroll
  for (int jj=0; jj<8; ++jj){
    float v = val[jj]*invL;
    val[jj] = v;
    s[jj] = v; q[jj] = v*v;
  }
  #pragma unroll
  for (int o2=1; o2<32; o2<<=1){
    #pragma unroll
    for (int jj=0; jj<8; ++jj){
      s[jj] += __shfl_xor(s[jj], o2);
      q[jj] += __shfl_xor(q[jj], o2);
    }
  }
  if (nl == 0){
    #pragma unroll
    for (int jj=0; jj<8; ++jj){
      int c = vq*8 + jj;
      psum[c*256 + bid] = s[jj];
      psq [c*256 + bid] = q[jj];
    }
  }
  __syncthreads();
  if (t == 0){
    __threadfence();
    atomicAdd(ctr, 1);
    while (__hip_atomic_load(ctr, __ATOMIC_ACQUIRE, __HIP_MEMORY_SCOPE_AGENT) < 256) {}
  }
  __syncthreads();
  __threadfence();                    // ensure fresh psum/psq visibility

  // cooperative stats: thread t -> channel t>>2, quarter t&3
  __shared__ float sL[64][4], qL[64][4], gainL[64], betaL[64];
  {
    int c4 = t >> 2, qq = t & 3;
    const float* pc = psum + c4*256 + qq*64;
    const float* qc = psq  + c4*256 + qq*64;
    float S = 0.f, Q = 0.f;
    #pragma unroll 8
    for (int j=0; j<64; ++j){ S += pc[j]; Q += qc[j]; }
    sL[c4][qq] = S; qL[c4][qq] = Q;
  }
  __syncthreads();
  if (t < 64){
    float S = sL[t][0]+sL[t][1]+sL[t][2]+sL[t][3];
    float Q = qL[t][0]+qL[t][1]+qL[t][2]+qL[t][3];
    float mu = S*(1.f/8192.f);
    float var = fmaxf(Q*(1.f/8192.f) - mu*mu, 0.f);
    float rstd = rsqrtf(var + 1e-5f);
    float gain = g[t]*rstd;
    gainL[t] = gain;
    betaL[t] = bb[t] - gain*mu;
  }
  __syncthreads();
  #pragma unroll
  for (int jj=0; jj<8; ++jj){
    int c = vq*8 + jj;
    float hv = lrelu_(gainL[c]*val[jj] + betaL[c]);
    hout[((size_t)b*CHN + c)*NPIX + rt*32 + nl] = hv;
  }
}

// ---------------- final 1x1 conv ----------------
__global__ __launch_bounds__(256) void final_kernel(const float* __restrict__ h,
                                                    const float* __restrict__ ow,
                                                    const float* __restrict__ ob,
                                                    float* __restrict__ out){
  int idx = blockIdx.x*256 + threadIdx.x;     // 819200
  int b  = idx / 409600;
  int r  = idx - b*409600;
  int oc = r >> 12;
  int n  = r & (NPIX-1);
  const float* hp = h + (size_t)b*CHN*NPIX + n;
  const float* wp = ow + oc*64;
  float acc = ob[oc];
  #pragma unroll
  for (int v=0; v<64; ++v) acc += wp[v]*hp[(size_t)v*NPIX];
  out[idx] = acc;
}

extern "C" void kernel_launch(void* const* d_in, const int* in_sizes, int n_in,
                              void* d_out, int out_size, void* d_ws, size_t ws_size,
                              hipStream_t stream){
  const float* x     = (const float*)d_in[0];
  const float* convw = (const float*)d_in[1];
  const float* convb = (const float*)d_in[2];
  const float* bn0g  = (const float*)d_in[3];
  const float* bn0b  = (const float*)d_in[4];
  const float* qw    = (const float*)d_in[5];
  const float* qbias = (const float*)d_in[6];
  const float* fkw   = (const float*)d_in[7];
  const float* fkb   = (const float*)d_in[8];
  const float* ckw   = (const float*)d_in[9];
  const float* ckb   = (const float*)d_in[10];
  const float* fvw   = (const float*)d_in[11];
  const float* fvb   = (const float*)d_in[12];
  const float* cvw   = (const float*)d_in[13];
  const float* cvb   = (const float*)d_in[14];
  const float* bng   = (const float*)d_in[15];
  const float* bnb   = (const float*)d_in[16];
  const float* ow    = (const float*)d_in[17];
  const float* ob    = (const float*)d_in[18];

  const size_t TEN = (size_t)2*CHN*NPIX;   // 524288 elements
  const size_t BFU = TEN/2;                // float-units per bf16 tensor
  float* ws   = (float*)d_ws;
  float* pos  = ws;                 // 131072
  float* h    = pos + 32*NPIX;      // 524288
  // --- contiguous zero region: k0, v0, kh0, kl0, vh0, vl0, ctr ---
  float* zbase = h + TEN;
  float* k0   = zbase;                          // TEN
  float* v0   = k0 + TEN;                       // TEN
  unsigned short* kh0 = (unsigned short*)(v0 + TEN);     // BFU f-units
  unsigned short* kl0 = (unsigned short*)(v0 + TEN + BFU);
  unsigned short* vh0 = (unsigned short*)(v0 + TEN + 2*BFU);
  unsigned short* vl0 = (unsigned short*)(v0 + TEN + 3*BFU);
  int*   ctr  = (int*)(v0 + TEN + 4*BFU);       // 16 ints (64B)
  const size_t ZBYTES = (2*TEN + 4*BFU)*4 + 64;
  float* nz   = v0 + TEN + 4*BFU + 16;
  float* k1   = nz;                 // TEN
  float* v1   = k1 + TEN;           // TEN
  unsigned short* kh1 = (unsigned short*)(v1 + TEN);
  unsigned short* kl1 = (unsigned short*)(v1 + TEN + BFU);
  unsigned short* vh1 = (unsigned short*)(v1 + TEN + 2*BFU);
  unsigned short* vl1 = (unsigned short*)(v1 + TEN + 3*BFU);
  float* stats = v1 + TEN + 4*BFU;  // 128
  float* psum = stats + 128;        // 64*256
  float* psq  = psum + 64*256;      // 64*256
  float* wt   = psq + 64*256;       // 381632
  unsigned short* qh = (unsigned short*)(wt + 381632);
  unsigned short* ql = (unsigned short*)(wt + 381632 + BFU);
  float* part = wt + 381632 + 2*BFU;  // 640 * 2112 floats

  hipMemsetAsync(zbase, 0, ZBYTES, stream);

  poswtr_kernel<<<2003,256,0,stream>>>(qw, fkw, ckw, fvw, cvw, convw, pos, wt);
  conv_in_kernel<<<2048,256,0,stream>>>(x, wt + 376832, convb, h);
  bn_stats_kernel<<<64,1024,0,stream>>>(h, stats);
  bn_apply_kernel<<<512,256,0,stream>>>(h, stats, bn0g, bn0b, h);

  float* kfp[2] = {k0,k1};
  float* vfp[2] = {v0,v1};
  unsigned short* khb[2] = {kh0,kh1};
  unsigned short* klb[2] = {kl0,kl1};
  unsigned short* vhb[2] = {vh0,vh1};
  unsigned short* vlb[2] = {vl0,vl1};
  for (int l=0; l<8; ++l){
    float* kold = kfp[l&1]; float* knew = kfp[(l+1)&1];
    float* vold = vfp[l&1]; float* vnew = vfp[(l+1)&1];
    cv1_kernel<<<1536,256,0,stream>>>(h, pos, kold, vold,
        wt + l*6144,
        wt + 49152 + l*10240,
        wt + 49152 + 81920 + l*10240,
        wt + 49152 + 2*81920 + l*10240,
        wt + 49152 + 3*81920 + l*10240,
        qbias + l*64, fkb + l*64, ckb + l*64, fvb + l*64, cvb + l*64,
        qh, ql,
        knew, khb[(l+1)&1], klb[(l+1)&1],
        vnew, vhb[(l+1)&1], vlb[(l+1)&1]);
    attn_mfma<<<640,128,0,stream>>>(qh, ql, khb[l&1], klb[l&1], vhb[l&1], vlb[l&1], part);
    attn_combine2<<<256,256,0,stream>>>(part, h, psum, psq, ctr + l,
                                        bng + l*64, bnb + l*64);
  }
  final_kernel<<<3200,256,0,stream>>>(h, ow, ob, (float*)d_out);
}

// Round 15
// 784.395 us; speedup vs baseline: 1.4145x; 1.4145x over previous
//
#include <hip/hip_runtime.h>

#define NPIX 4096
#define CHN  64

typedef __attribute__((ext_vector_type(8))) short short8;
typedef __attribute__((ext_vector_type(8))) unsigned short ushort8;
typedef __attribute__((ext_vector_type(4))) unsigned short ushort4v;
typedef __attribute__((ext_vector_type(4))) float f32x4;

__device__ __forceinline__ float lrelu_(float x){ return x >= 0.f ? x : 0.01f*x; }

__device__ __forceinline__ unsigned short f2bf(float x){
  union { float f; unsigned u; } v; v.f = x;
  unsigned r = v.u + 0x7FFF + ((v.u >> 16) & 1);
  return (unsigned short)(r >> 16);
}
__device__ __forceinline__ float bf2f(unsigned short h){
  union { unsigned u; float f; } v; v.u = ((unsigned)h) << 16;
  return v.f;
}

// ---------------- fused positional table + weight transpose ----------------
__global__ void poswtr_kernel(const float* __restrict__ qw, const float* __restrict__ fkw,
                              const float* __restrict__ ckw, const float* __restrict__ fvw,
                              const float* __restrict__ cvw, const float* __restrict__ convw,
                              float* __restrict__ pos, float* __restrict__ wt){
  int gid = blockIdx.x*256 + threadIdx.x;
  if (gid < 131072){
    int c = gid >> 12;
    int n = gid & (NPIX-1);
    int bcoord = (c < 16) ? (n >> 6) : (n & 63);
    int a = (c < 16) ? c : (c - 16);
    int flat = a*64 + bcoord;
    int p = flat >> 4;
    int j = flat & 15;
    float val = 0.f;
    if (p != 0){
      float ex = (float)(j & ~1) * (1.f/16.f);
      float w = powf(10000.f, -ex);
      float ang = (float)p * w;
      val = (j & 1) ? cosf(ang) : sinf(ang);
    }
    pos[gid] = val;
    return;
  }
  int idx = gid - 131072;
  if (idx >= 381632) return;
  if (idx < 49152){
    int l = idx / 6144, r = idx % 6144, i = r >> 6, o = r & 63;
    wt[idx] = qw[(l*64 + o)*96 + i];
  } else if (idx < 376832){
    int e = idx - 49152;
    int mat = e / 81920, r = e % 81920;
    int l = r / 10240, rr = r % 10240, i = rr >> 6, o = rr & 63;
    const float* src = (mat==0) ? fkw : (mat==1) ? ckw : (mat==2) ? fvw : cvw;
    wt[idx] = src[(l*64 + o)*160 + i];
  } else {
    int e = idx - 376832;
    int o = e & 63, tap = e >> 6;
    int ci = tap / 25, r = tap % 25;
    wt[idx] = convw[(o*3 + ci)*25 + r];
  }
}

// ---------------- masked causal 5x5 conv (input layer) ----------------
__global__ __launch_bounds__(256) void conv_in_kernel(const float* __restrict__ x,
                                                      const float* __restrict__ cwt,
                                                      const float* __restrict__ cb,
                                                      float* __restrict__ out){
  int t = threadIdx.x;
  int o = t & 63;
  int sub = t >> 6;
  int bid = blockIdx.x;
  int b = bid >> 10;
  int n = ((bid & 1023) << 2) + sub;
  int y = n >> 6, xx = n & 63;
  float acc = cb[o];
  #pragma unroll
  for (int ci=0; ci<3; ++ci){
    const float* xp = x + ((b*3+ci)<<12);
    #pragma unroll
    for (int ky=0; ky<3; ++ky){
      int yy = y + ky - 2;
      if (yy < 0) continue;
      int nk = (ky==2) ? 2 : 5;
      #pragma unroll
      for (int kx=0; kx<5; ++kx){
        if (kx >= nk) break;
        int xc = xx + kx - 2;
        if (xc < 0 || xc > 63) continue;
        acc += xp[(yy<<6) + xc] * cwt[(ci*25 + ky*5 + kx)*64 + o];
      }
    }
  }
  out[(b*CHN+o)*NPIX + n] = acc;
}

// ---------------- batch-norm stats (conv path only) ----------------
__global__ __launch_bounds__(1024) void bn_stats_kernel(const float* __restrict__ xin,
                                                        float* __restrict__ stats){
  int c = blockIdx.x;
  int t = threadIdx.x;
  float s = 0.f, ss = 0.f;
  #pragma unroll
  for (int it=0; it<8; ++it){
    int idx = t + it*1024;
    float v = xin[(((idx>>12))*CHN + c)*NPIX + (idx & (NPIX-1))];
    s += v; ss += v*v;
  }
  #pragma unroll
  for (int o=1; o<64; o<<=1){ s += __shfl_xor(s,o); ss += __shfl_xor(ss,o); }
  __shared__ float ps[16], pq[16];
  if ((t & 63) == 0){ ps[t>>6] = s; pq[t>>6] = ss; }
  __syncthreads();
  if (t == 0){
    float S=0.f, Q=0.f;
    #pragma unroll
    for (int i=0;i<16;++i){ S += ps[i]; Q += pq[i]; }
    float mu = S*(1.f/8192.f);
    float var = Q*(1.f/8192.f) - mu*mu;
    var = fmaxf(var, 0.f);
    stats[c*2]   = mu;
    stats[c*2+1] = rsqrtf(var + 1e-5f);
  }
}

// ---------------- BN apply + LeakyReLU (conv path) ----------------
__global__ void bn_apply_kernel(const float* __restrict__ xin, const float* __restrict__ stats,
                                const float* __restrict__ g, const float* __restrict__ bb,
                                float* __restrict__ hout){
  int idx = blockIdx.x*256 + threadIdx.x;
  int e = idx << 2;
  int c = (e >> 12) & 63;
  float mu = stats[c*2], rstd = stats[c*2+1];
  float gain = g[c]*rstd;
  float beta = bb[c] - gain*mu;
  float4 v = *(const float4*)(xin + e);
  float4 r;
  r.x = lrelu_(gain*v.x + beta);
  r.y = lrelu_(gain*v.y + beta);
  r.z = lrelu_(gain*v.z + beta);
  r.w = lrelu_(gain*v.w + beta);
  *(float4*)(hout + e) = r;
}

// ---------------- BN apply + LeakyReLU from per-seg partials (in-place) ---
__global__ __launch_bounds__(256) void bn_apply2_kernel(float* __restrict__ hbuf,
                                                        const float* __restrict__ psum,
                                                        const float* __restrict__ psq,
                                                        const float* __restrict__ g,
                                                        const float* __restrict__ bb){
  int bid = blockIdx.x;
  int ebase = bid << 10;
  int c = (ebase >> 12) & 63;
  int t = threadIdx.x;
  float s = psum[c*256 + t];
  float q = psq[c*256 + t];
  #pragma unroll
  for (int o=1; o<64; o<<=1){ s += __shfl_xor(s,o); q += __shfl_xor(q,o); }
  __shared__ float as[4], aq[4];
  if ((t & 63) == 0){ as[t>>6] = s; aq[t>>6] = q; }
  __syncthreads();
  float S = as[0]+as[1]+as[2]+as[3];
  float Q = aq[0]+aq[1]+aq[2]+aq[3];
  float mu = S*(1.f/8192.f);
  float var = fmaxf(Q*(1.f/8192.f) - mu*mu, 0.f);
  float rstd = rsqrtf(var + 1e-5f);
  float gain = g[c]*rstd;
  float beta = bb[c] - gain*mu;
  float4 v = *(const float4*)(hbuf + ebase + t*4);
  float4 r;
  r.x = lrelu_(gain*v.x + beta);
  r.y = lrelu_(gain*v.y + beta);
  r.z = lrelu_(gain*v.z + beta);
  r.w = lrelu_(gain*v.w + beta);
  *(float4*)(hbuf + ebase + t*4) = r;
}

// ---------------- five 1x1 convs, section-split ----------------
// grid 1536 = sec(3) x b(2) x tile(256 of 16 px); block 256 = 4 waves x 4 px.
__global__ __launch_bounds__(256) void cv1_kernel(
    const float* __restrict__ hbuf, const float* __restrict__ pos,
    const float* __restrict__ kold, const float* __restrict__ vold,
    const float* __restrict__ qwt,
    const float* __restrict__ fkwt, const float* __restrict__ ckwt,
    const float* __restrict__ fvwt, const float* __restrict__ cvwt,
    const float* __restrict__ qbi,  const float* __restrict__ fkb,
    const float* __restrict__ ckb,  const float* __restrict__ fvb,
    const float* __restrict__ cvb,
    unsigned short* __restrict__ qh, unsigned short* __restrict__ ql,
    float* __restrict__ knew, unsigned short* __restrict__ khn, unsigned short* __restrict__ kln,
    float* __restrict__ vnew, unsigned short* __restrict__ vhTn, unsigned short* __restrict__ vlTn)
{
  int t = threadIdx.x;
  int o  = t & 63;
  int wv = t >> 6;                      // 0..3
  int sec  = blockIdx.x >> 9;           // 0,1,2
  int bid  = blockIdx.x & 511;
  int b    = bid >> 8;
  int tile = bid & 255;
  int n0 = tile*16 + wv*4;

  const float* hb = hbuf + b*CHN*NPIX + n0;
  const float* pb = pos + n0;

  auto load4 = [&](const float* p, float* dst){
    float4 a = *(const float4*)p;
    dst[0]=a.x; dst[1]=a.y; dst[2]=a.z; dst[3]=a.w;
  };

  float x[4];
  long obase = (long)(b*CHN+o)*NPIX + n0;
  size_t nbase = ((size_t)b*NPIX + n0)*64 + o;

  if (sec == 0){
    float aq[4];
    float bias = qbi[o];
    #pragma unroll
    for (int j=0;j<4;++j) aq[j]=bias;
    #pragma unroll 4
    for (int i=0;i<64;++i){
      load4(hb + i*NPIX, x);
      float w = qwt[i*64 + o];
      #pragma unroll
      for (int j=0;j<4;++j) aq[j] += w*x[j];
    }
    #pragma unroll 4
    for (int i=0;i<32;++i){
      load4(pb + i*NPIX, x);
      float w = qwt[(64+i)*64 + o];
      #pragma unroll
      for (int j=0;j<4;++j) aq[j] += w*x[j];
    }
    const float QS = 0.125f;            // expf-domain softmax
    #pragma unroll
    for (int j=0;j<4;++j){
      float v = lrelu_(aq[j]) * QS;
      unsigned short hb16 = f2bf(v);
      qh[nbase + (size_t)j*64] = hb16;
      ql[nbase + (size_t)j*64] = f2bf(v - bf2f(hb16));
    }
  } else if (sec == 1){
    const float* kb = kold + b*CHN*NPIX + n0;
    float af[4], ac[4];
    float bf = fkb[o], bc = ckb[o];
    #pragma unroll
    for (int j=0;j<4;++j){ af[j]=bf; ac[j]=bc; }
    #pragma unroll 4
    for (int i=0;i<64;++i){
      load4(hb + i*NPIX, x);
      float wf = fkwt[i*64+o], wc = ckwt[i*64+o];
      #pragma unroll
      for (int j=0;j<4;++j){ af[j] += wf*x[j]; ac[j] += wc*x[j]; }
    }
    #pragma unroll 4
    for (int i=0;i<32;++i){
      load4(pb + i*NPIX, x);
      float wf = fkwt[(64+i)*64+o], wc = ckwt[(64+i)*64+o];
      #pragma unroll
      for (int j=0;j<4;++j){ af[j] += wf*x[j]; ac[j] += wc*x[j]; }
    }
    #pragma unroll 4
    for (int i=0;i<64;++i){
      load4(kb + i*NPIX, x);
      float wf = fkwt[(96+i)*64+o], wc = ckwt[(96+i)*64+o];
      #pragma unroll
      for (int j=0;j<4;++j){ af[j] += wf*x[j]; ac[j] += wc*x[j]; }
    }
    float kv[4];
    load4(kb + o*NPIX, kv);
    #pragma unroll
    for (int j=0;j<4;++j){
      float fk = 1.f/(1.f+__expf(-af[j]));
      float kn = fk*kv[j] + lrelu_(ac[j]);
      knew[obase+j] = kn;
      unsigned short hb16 = f2bf(kn);
      khn[nbase + (size_t)j*64] = hb16;
      kln[nbase + (size_t)j*64] = f2bf(kn - bf2f(hb16));
    }
  } else {
    const float* vb = vold + b*CHN*NPIX + n0;
    float af[4], ac[4];
    float bf = fvb[o], bc = cvb[o];
    #pragma unroll
    for (int j=0;j<4;++j){ af[j]=bf; ac[j]=bc; }
    #pragma unroll 4
    for (int i=0;i<64;++i){
      load4(hb + i*NPIX, x);
      float wf = fvwt[i*64+o], wc = cvwt[i*64+o];
      #pragma unroll
      for (int j=0;j<4;++j){ af[j] += wf*x[j]; ac[j] += wc*x[j]; }
    }
    #pragma unroll 4
    for (int i=0;i<32;++i){
      load4(pb + i*NPIX, x);
      float wf = fvwt[(64+i)*64+o], wc = cvwt[(64+i)*64+o];
      #pragma unroll
      for (int j=0;j<4;++j){ af[j] += wf*x[j]; ac[j] += wc*x[j]; }
    }
    #pragma unroll 4
    for (int i=0;i<64;++i){
      load4(vb + i*NPIX, x);
      float wf = fvwt[(96+i)*64+o], wc = cvwt[(96+i)*64+o];
      #pragma unroll
      for (int j=0;j<4;++j){ af[j] += wf*x[j]; ac[j] += wc*x[j]; }
    }
    float vv[4];
    load4(vb + o*NPIX, vv);
    ushort4v vph, vpl;
    #pragma unroll
    for (int j=0;j<4;++j){
      float fv = 1.f/(1.f+__expf(-af[j]));
      float vn = fv*vv[j] + lrelu_(ac[j]);
      vnew[obase+j] = vn;
      unsigned short hb16 = f2bf(vn);
      vph[j] = hb16;
      vpl[j] = f2bf(vn - bf2f(hb16));
    }
    *(ushort4v*)(vhTn + ((size_t)(b*CHN+o))*NPIX + n0) = vph;
    *(ushort4v*)(vlTn + ((size_t)(b*CHN+o))*NPIX + n0) = vpl;
  }
}

// ---------------- MFMA flash attention (16x16x32, 640 blocks) ----
__global__ __launch_bounds__(128) void attn_mfma(
    const unsigned short* __restrict__ qhg, const unsigned short* __restrict__ qlg,
    const unsigned short* __restrict__ khg, const unsigned short* __restrict__ klg,
    const unsigned short* __restrict__ vhg, const unsigned short* __restrict__ vlg,
    float* __restrict__ part)
{
  int bid = 639 - (int)blockIdx.x;           // longest bands dispatched first
  int b = 0, id = bid;
  if (id >= 320){ b = 1; id -= 320; }
  int pidx = bid;
  int rem = id, k = 0;
  while (rem >= 32*(k+1)){ rem -= 32*(k+1); ++k; }
  int rt    = 32*k + rem/(k+1);
  int chunk = rem - (rem/(k+1))*(k+1);

  int C0  = chunk << 10;                      // 1024*chunk
  int end = min(C0 + 1024, rt*32 + 32);
  int nt  = (end - C0 + 63) >> 6;

  int t = threadIdx.x;
  int w = t >> 6;
  int l = t & 63;
  int r = l & 15;
  int g = l >> 4;
  int n_g = rt*32 + w*16 + r;                 // this lane's q-row

  __shared__ __align__(16) char KH[8192], KL[8192];
  __shared__ __align__(16) char VH[8192], VL[8192];
  __shared__ __align__(16) char PH[2][2048], PL[2][2048];

  const unsigned short* qhp = qhg + (size_t)b*NPIX*64;
  const unsigned short* qlp = qlg + (size_t)b*NPIX*64;
  const unsigned short* khp = khg + (size_t)b*NPIX*64;
  const unsigned short* klp = klg + (size_t)b*NPIX*64;
  const unsigned short* vhp = vhg + (size_t)b*CHN*NPIX;
  const unsigned short* vlp = vlg + (size_t)b*CHN*NPIX;

  short8 qh0 = *(const short8*)(qhp + (size_t)n_g*64 + 8*g);
  short8 qh1 = *(const short8*)(qhp + (size_t)n_g*64 + 8*g + 32);
  short8 ql0 = *(const short8*)(qlp + (size_t)n_g*64 + 8*g);
  short8 ql1 = *(const short8*)(qlp + (size_t)n_g*64 + 8*g + 32);

  int srow[4], scc8[4], soff[4];
  #pragma unroll
  for (int p=0; p<4; ++p){
    int slot = t + (p<<7);
    int row = slot >> 3, cc = slot & 7;
    srow[p] = row; scc8[p] = cc*8;
    soff[p] = row*128 + ((cc ^ (row & 7)) << 4);
  }

  ushort8 rkh[4], rkl[4], rvh[4], rvl[4];
  auto issue = [&](int m0){
    #pragma unroll
    for (int p=0; p<4; ++p){
      rkh[p] = *(const ushort8*)(khp + (size_t)(m0+srow[p])*64 + scc8[p]);
      rkl[p] = *(const ushort8*)(klp + (size_t)(m0+srow[p])*64 + scc8[p]);
      rvh[p] = *(const ushort8*)(vhp + (size_t)srow[p]*NPIX + m0 + scc8[p]);
      rvl[p] = *(const ushort8*)(vlp + (size_t)srow[p]*NPIX + m0 + scc8[p]);
    }
  };

  f32x4 zero4 = {0.f,0.f,0.f,0.f};
  f32x4 oacc[4];
  #pragma unroll
  for (int vf=0; vf<4; ++vf) oacc[vf] = zero4;
  float m_run = -1e30f, l_run = 0.f;

  int nmax_w = rt*32 + w*16 + 15;

  issue(C0);
  for (int ti=0; ti<nt; ++ti){
    int m0 = C0 + (ti<<6);
    __syncthreads();
    #pragma unroll
    for (int p=0; p<4; ++p){
      *(ushort8*)(KH + soff[p]) = rkh[p];
      *(ushort8*)(KL + soff[p]) = rkl[p];
      *(ushort8*)(VH + soff[p]) = rvh[p];
      *(ushort8*)(VL + soff[p]) = rvl[p];
    }
    __syncthreads();
    if (ti+1 < nt) issue(m0 + 64);

    if (m0 <= nmax_w){
      f32x4 sf[4];
      #pragma unroll
      for (int mf=0; mf<4; ++mf) sf[mf] = zero4;
      #pragma unroll
      for (int kc=0; kc<2; ++kc){
        short8 qfh = kc ? qh1 : qh0;
        short8 qfl = kc ? ql1 : ql0;
        int ch = ((g + 4*kc) ^ (r & 7)) << 4;
        #pragma unroll
        for (int mf=0; mf<4; ++mf){
          int ro = (16*mf + r)*128;
          short8 ah = *(const short8*)(KH + ro + ch);
          short8 al = *(const short8*)(KL + ro + ch);
          sf[mf] = __builtin_amdgcn_mfma_f32_16x16x32_bf16(ah, qfh, sf[mf], 0,0,0);
          sf[mf] = __builtin_amdgcn_mfma_f32_16x16x32_bf16(al, qfh, sf[mf], 0,0,0);
          sf[mf] = __builtin_amdgcn_mfma_f32_16x16x32_bf16(ah, qfl, sf[mf], 0,0,0);
        }
      }
      float pv[16];
      float mx = -1e30f;
      #pragma unroll
      for (int mf=0; mf<4; ++mf){
        #pragma unroll
        for (int q2=0; q2<4; ++q2){
          int mg = m0 + 16*mf + 4*g + q2;
          float s = sf[mf][q2];
          s = (mg <= n_g) ? s : -1e30f;
          pv[mf*4+q2] = s;
          mx = fmaxf(mx, s);
        }
      }
      mx = fmaxf(mx, __shfl_xor(mx, 16));
      mx = fmaxf(mx, __shfl_xor(mx, 32));
      float m_new = fmaxf(m_run, mx);
      float alpha = __expf(m_run - m_new);
      float ps = 0.f;
      #pragma unroll
      for (int i=0; i<16; ++i){ pv[i] = __expf(pv[i] - m_new); ps += pv[i]; }
      ps += __shfl_xor(ps, 16);
      ps += __shfl_xor(ps, 32);
      l_run = l_run*alpha + ps;
      m_run = m_new;

      #pragma unroll
      for (int mf=0; mf<4; ++mf){
        unsigned short h_[4], l_[4];
        #pragma unroll
        for (int q2=0; q2<4; ++q2){
          float xv = pv[mf*4+q2];
          h_[q2] = f2bf(xv);
          l_[q2] = f2bf(xv - bf2f(h_[q2]));
        }
        int addr = r*128 + ((((g>>1) + 2*mf) ^ (r & 7)) << 4) + ((g&1)<<3);
        uint2 wh = make_uint2((unsigned)h_[0] | ((unsigned)h_[1]<<16),
                              (unsigned)h_[2] | ((unsigned)h_[3]<<16));
        uint2 wl = make_uint2((unsigned)l_[0] | ((unsigned)l_[1]<<16),
                              (unsigned)l_[2] | ((unsigned)l_[3]<<16));
        *(uint2*)(PH[w] + addr) = wh;
        *(uint2*)(PL[w] + addr) = wl;
      }
      #pragma unroll
      for (int vf=0; vf<4; ++vf) oacc[vf] *= alpha;

      #pragma unroll
      for (int kc=0; kc<2; ++kc){
        int ch = ((g + 4*kc) ^ (r & 7)) << 4;
        short8 pfh = *(const short8*)(PH[w] + r*128 + ch);
        short8 pfl = *(const short8*)(PL[w] + r*128 + ch);
        #pragma unroll
        for (int vf=0; vf<4; ++vf){
          int ro = (16*vf + r)*128;
          short8 ah = *(const short8*)(VH + ro + ch);
          short8 al = *(const short8*)(VL + ro + ch);
          oacc[vf] = __builtin_amdgcn_mfma_f32_16x16x32_bf16(ah, pfh, oacc[vf], 0,0,0);
          oacc[vf] = __builtin_amdgcn_mfma_f32_16x16x32_bf16(al, pfh, oacc[vf], 0,0,0);
          oacc[vf] = __builtin_amdgcn_mfma_f32_16x16x32_bf16(ah, pfl, oacc[vf], 0,0,0);
        }
      }
    }
  }

  float* pacc = part + (size_t)pidx * 2112;
  int nl = w*16 + r;
  #pragma unroll
  for (int vf=0; vf<4; ++vf)
    *(f32x4*)(pacc + nl*64 + 16*vf + 4*g) = oacc[vf];
  if (g == 0){
    pacc[2048 + nl*2]   = m_run;
    pacc[2048 + nl*2+1] = l_run;
  }
}

// ---------------- attention phase 2: combine partials + emit BN partial sums ----
__global__ __launch_bounds__(256) void attn_combine(const float* __restrict__ part,
                                                    float* __restrict__ out1,
                                                    float* __restrict__ psum,
                                                    float* __restrict__ psq){
  int bid = blockIdx.x;               // b*128 + rt
  int b = bid >> 7, rt = bid & 127;
  int k = rt >> 5;
  int nch = k + 1;                    // <= 4
  int base = b*320 + 16*k*(k+1) + (rt - 32*k)*nch;

  int t = threadIdx.x;
  int nl = t & 31, vq = t >> 5;       // 32 rows x 8 vd-octets

  float M = -1e30f;
  #pragma unroll
  for (int c=0; c<4; ++c)
    if (c < nch) M = fmaxf(M, part[(size_t)(base+c)*2112 + 2048 + nl*2]);

  float L = 0.f;
  float val[8];
  #pragma unroll
  for (int jj=0; jj<8; ++jj) val[jj] = 0.f;
  #pragma unroll
  for (int c=0; c<4; ++c){
    if (c < nch){
      const float* pa = part + (size_t)(base+c)*2112;
      float wgt = __expf(pa[2048 + nl*2] - M);
      L += pa[2048 + nl*2 + 1] * wgt;
      #pragma unroll
      for (int jj=0; jj<8; ++jj) val[jj] += wgt * pa[nl*64 + vq*8 + jj];
    }
  }
  float invL = 1.f / L;
  float s[8], q[8];
  #pragma unroll
  for (int jj=0; jj<8; ++jj){
    float v = val[jj]*invL;
    out1[((size_t)b*CHN + vq*8 + jj)*NPIX + rt*32 + nl] = v;
    s[jj] = v; q[jj] = v*v;
  }
  #pragma unroll
  for (int o2=1; o2<32; o2<<=1){
    #pragma unroll
    for (int jj=0; jj<8; ++jj){
      s[jj] += __shfl_xor(s[jj], o2);
      q[jj] += __shfl_xor(q[jj], o2);
    }
  }
  if (nl == 0){
    #pragma unroll
    for (int jj=0; jj<8; ++jj){
      int c = vq*8 + jj;
      psum[c*256 + bid] = s[jj];
      psq [c*256 + bid] = q[jj];
    }
  }
}

// ---------------- final 1x1 conv ----------------
__global__ __launch_bounds__(256) void final_kernel(const float* __restrict__ h,
                                                    const float* __restrict__ ow,
                                                    const float* __restrict__ ob,
                                                    float* __restrict__ out){
  int idx = blockIdx.x*256 + threadIdx.x;     // 819200
  int b  = idx / 409600;
  int r  = idx - b*409600;
  int oc = r >> 12;
  int n  = r & (NPIX-1);
  const float* hp = h + (size_t)b*CHN*NPIX + n;
  const float* wp = ow + oc*64;
  float acc = ob[oc];
  #pragma unroll
  for (int v=0; v<64; ++v) acc += wp[v]*hp[(size_t)v*NPIX];
  out[idx] = acc;
}

extern "C" void kernel_launch(void* const* d_in, const int* in_sizes, int n_in,
                              void* d_out, int out_size, void* d_ws, size_t ws_size,
                              hipStream_t stream){
  const float* x     = (const float*)d_in[0];
  const float* convw = (const float*)d_in[1];
  const float* convb = (const float*)d_in[2];
  const float* bn0g  = (const float*)d_in[3];
  const float* bn0b  = (const float*)d_in[4];
  const float* qw    = (const float*)d_in[5];
  const float* qbias = (const float*)d_in[6];
  const float* fkw   = (const float*)d_in[7];
  const float* fkb   = (const float*)d_in[8];
  const float* ckw   = (const float*)d_in[9];
  const float* ckb   = (const float*)d_in[10];
  const float* fvw   = (const float*)d_in[11];
  const float* fvb   = (const float*)d_in[12];
  const float* cvw   = (const float*)d_in[13];
  const float* cvb   = (const float*)d_in[14];
  const float* bng   = (const float*)d_in[15];
  const float* bnb   = (const float*)d_in[16];
  const float* ow    = (const float*)d_in[17];
  const float* ob    = (const float*)d_in[18];

  const size_t TEN = (size_t)2*CHN*NPIX;   // 524288 elements
  const size_t BFU = TEN/2;                // float-units per bf16 tensor
  float* ws   = (float*)d_ws;
  float* pos  = ws;                 // 131072
  float* h    = pos + 32*NPIX;      // 524288
  // --- contiguous zero region: k0, v0, kh0, kl0, vh0, vl0 (+pad) ---
  float* zbase = h + TEN;
  float* k0   = zbase;                          // TEN
  float* v0   = k0 + TEN;                       // TEN
  unsigned short* kh0 = (unsigned short*)(v0 + TEN);     // BFU f-units
  unsigned short* kl0 = (unsigned short*)(v0 + TEN + BFU);
  unsigned short* vh0 = (unsigned short*)(v0 + TEN + 2*BFU);
  unsigned short* vl0 = (unsigned short*)(v0 + TEN + 3*BFU);
  const size_t ZBYTES = (2*TEN + 4*BFU)*4 + 64;
  float* nz   = v0 + TEN + 4*BFU + 16;
  float* k1   = nz;                 // TEN
  float* v1   = k1 + TEN;           // TEN
  unsigned short* kh1 = (unsigned short*)(v1 + TEN);
  unsigned short* kl1 = (unsigned short*)(v1 + TEN + BFU);
  unsigned short* vh1 = (unsigned short*)(v1 + TEN + 2*BFU);
  unsigned short* vl1 = (unsigned short*)(v1 + TEN + 3*BFU);
  float* stats = v1 + TEN + 4*BFU;  // 128
  float* psum = stats + 128;        // 64*256
  float* psq  = psum + 64*256;      // 64*256
  float* wt   = psq + 64*256;       // 381632
  unsigned short* qh = (unsigned short*)(wt + 381632);
  unsigned short* ql = (unsigned short*)(wt + 381632 + BFU);
  float* part = wt + 381632 + 2*BFU;  // 640 * 2112 floats

  hipMemsetAsync(zbase, 0, ZBYTES, stream);

  poswtr_kernel<<<2003,256,0,stream>>>(qw, fkw, ckw, fvw, cvw, convw, pos, wt);
  conv_in_kernel<<<2048,256,0,stream>>>(x, wt + 376832, convb, h);
  bn_stats_kernel<<<64,1024,0,stream>>>(h, stats);
  bn_apply_kernel<<<512,256,0,stream>>>(h, stats, bn0g, bn0b, h);

  float* kfp[2] = {k0,k1};
  float* vfp[2] = {v0,v1};
  unsigned short* khb[2] = {kh0,kh1};
  unsigned short* klb[2] = {kl0,kl1};
  unsigned short* vhb[2] = {vh0,vh1};
  unsigned short* vlb[2] = {vl0,vl1};
  for (int l=0; l<8; ++l){
    float* kold = kfp[l&1]; float* knew = kfp[(l+1)&1];
    float* vold = vfp[l&1]; float* vnew = vfp[(l+1)&1];
    cv1_kernel<<<1536,256,0,stream>>>(h, pos, kold, vold,
        wt + l*6144,
        wt + 49152 + l*10240,
        wt + 49152 + 81920 + l*10240,
        wt + 49152 + 2*81920 + l*10240,
        wt + 49152 + 3*81920 + l*10240,
        qbias + l*64, fkb + l*64, ckb + l*64, fvb + l*64, cvb + l*64,
        qh, ql,
        knew, khb[(l+1)&1], klb[(l+1)&1],
        vnew, vhb[(l+1)&1], vlb[(l+1)&1]);
    attn_mfma<<<640,128,0,stream>>>(qh, ql, khb[l&1], klb[l&1], vhb[l&1], vlb[l&1], part);
    attn_combine<<<256,256,0,stream>>>(part, h, psum, psq);
    bn_apply2_kernel<<<512,256,0,stream>>>(h, psum, psq, bng + l*64, bnb + l*64);
  }
  final_kernel<<<3200,256,0,stream>>>(h, ow, ob, (float*)d_out);
}

// Round 16
// 780.227 us; speedup vs baseline: 1.4220x; 1.0053x over previous
//
#include <hip/hip_runtime.h>

#define NPIX 4096
#define CHN  64

typedef __attribute__((ext_vector_type(8))) short short8;
typedef __attribute__((ext_vector_type(8))) unsigned short ushort8;
typedef __attribute__((ext_vector_type(4))) unsigned short ushort4v;
typedef __attribute__((ext_vector_type(4))) float f32x4;

__device__ __forceinline__ float lrelu_(float x){ return x >= 0.f ? x : 0.01f*x; }

__device__ __forceinline__ unsigned short f2bf(float x){
  union { float f; unsigned u; } v; v.f = x;
  unsigned r = v.u + 0x7FFF + ((v.u >> 16) & 1);
  return (unsigned short)(r >> 16);
}
__device__ __forceinline__ float bf2f(unsigned short h){
  union { unsigned u; float f; } v; v.u = ((unsigned)h) << 16;
  return v.f;
}

// ---------------- fused positional table + weight transpose ----------------
__global__ void poswtr_kernel(const float* __restrict__ qw, const float* __restrict__ fkw,
                              const float* __restrict__ ckw, const float* __restrict__ fvw,
                              const float* __restrict__ cvw, const float* __restrict__ convw,
                              float* __restrict__ pos, float* __restrict__ wt){
  int gid = blockIdx.x*256 + threadIdx.x;
  if (gid < 131072){
    int c = gid >> 12;
    int n = gid & (NPIX-1);
    int bcoord = (c < 16) ? (n >> 6) : (n & 63);
    int a = (c < 16) ? c : (c - 16);
    int flat = a*64 + bcoord;
    int p = flat >> 4;
    int j = flat & 15;
    float val = 0.f;
    if (p != 0){
      float ex = (float)(j & ~1) * (1.f/16.f);
      float w = powf(10000.f, -ex);
      float ang = (float)p * w;
      val = (j & 1) ? cosf(ang) : sinf(ang);
    }
    pos[gid] = val;
    return;
  }
  int idx = gid - 131072;
  if (idx >= 381632) return;
  if (idx < 49152){
    int l = idx / 6144, r = idx % 6144, i = r >> 6, o = r & 63;
    wt[idx] = qw[(l*64 + o)*96 + i];
  } else if (idx < 376832){
    int e = idx - 49152;
    int mat = e / 81920, r = e % 81920;
    int l = r / 10240, rr = r % 10240, i = rr >> 6, o = rr & 63;
    const float* src = (mat==0) ? fkw : (mat==1) ? ckw : (mat==2) ? fvw : cvw;
    wt[idx] = src[(l*64 + o)*160 + i];
  } else {
    int e = idx - 376832;
    int o = e & 63, tap = e >> 6;
    int ci = tap / 25, r = tap % 25;
    wt[idx] = convw[(o*3 + ci)*25 + r];
  }
}

// ---------------- masked causal 5x5 conv (input layer) ----------------
__global__ __launch_bounds__(256) void conv_in_kernel(const float* __restrict__ x,
                                                      const float* __restrict__ cwt,
                                                      const float* __restrict__ cb,
                                                      float* __restrict__ out){
  int t = threadIdx.x;
  int o = t & 63;
  int sub = t >> 6;
  int bid = blockIdx.x;
  int b = bid >> 10;
  int n = ((bid & 1023) << 2) + sub;
  int y = n >> 6, xx = n & 63;
  float acc = cb[o];
  #pragma unroll
  for (int ci=0; ci<3; ++ci){
    const float* xp = x + ((b*3+ci)<<12);
    #pragma unroll
    for (int ky=0; ky<3; ++ky){
      int yy = y + ky - 2;
      if (yy < 0) continue;
      int nk = (ky==2) ? 2 : 5;
      #pragma unroll
      for (int kx=0; kx<5; ++kx){
        if (kx >= nk) break;
        int xc = xx + kx - 2;
        if (xc < 0 || xc > 63) continue;
        acc += xp[(yy<<6) + xc] * cwt[(ci*25 + ky*5 + kx)*64 + o];
      }
    }
  }
  out[(b*CHN+o)*NPIX + n] = acc;
}

// ---------------- batch-norm stats (conv path only) ----------------
__global__ __launch_bounds__(1024) void bn_stats_kernel(const float* __restrict__ xin,
                                                        float* __restrict__ stats){
  int c = blockIdx.x;
  int t = threadIdx.x;
  float s = 0.f, ss = 0.f;
  #pragma unroll
  for (int it=0; it<8; ++it){
    int idx = t + it*1024;
    float v = xin[(((idx>>12))*CHN + c)*NPIX + (idx & (NPIX-1))];
    s += v; ss += v*v;
  }
  #pragma unroll
  for (int o=1; o<64; o<<=1){ s += __shfl_xor(s,o); ss += __shfl_xor(ss,o); }
  __shared__ float ps[16], pq[16];
  if ((t & 63) == 0){ ps[t>>6] = s; pq[t>>6] = ss; }
  __syncthreads();
  if (t == 0){
    float S=0.f, Q=0.f;
    #pragma unroll
    for (int i=0;i<16;++i){ S += ps[i]; Q += pq[i]; }
    float mu = S*(1.f/8192.f);
    float var = Q*(1.f/8192.f) - mu*mu;
    var = fmaxf(var, 0.f);
    stats[c*2]   = mu;
    stats[c*2+1] = rsqrtf(var + 1e-5f);
  }
}

// ---------------- BN apply + LeakyReLU (conv path) ----------------
__global__ void bn_apply_kernel(const float* __restrict__ xin, const float* __restrict__ stats,
                                const float* __restrict__ g, const float* __restrict__ bb,
                                float* __restrict__ hout){
  int idx = blockIdx.x*256 + threadIdx.x;
  int e = idx << 2;
  int c = (e >> 12) & 63;
  float mu = stats[c*2], rstd = stats[c*2+1];
  float gain = g[c]*rstd;
  float beta = bb[c] - gain*mu;
  float4 v = *(const float4*)(xin + e);
  float4 r;
  r.x = lrelu_(gain*v.x + beta);
  r.y = lrelu_(gain*v.y + beta);
  r.z = lrelu_(gain*v.z + beta);
  r.w = lrelu_(gain*v.w + beta);
  *(float4*)(hout + e) = r;
}

// ---------------- BN apply + LeakyReLU from per-seg partials (in-place) ---
__global__ __launch_bounds__(256) void bn_apply2_kernel(float* __restrict__ hbuf,
                                                        const float* __restrict__ psum,
                                                        const float* __restrict__ psq,
                                                        const float* __restrict__ g,
                                                        const float* __restrict__ bb){
  int bid = blockIdx.x;
  int ebase = bid << 10;
  int c = (ebase >> 12) & 63;
  int t = threadIdx.x;
  float s = psum[c*256 + t];
  float q = psq[c*256 + t];
  #pragma unroll
  for (int o=1; o<64; o<<=1){ s += __shfl_xor(s,o); q += __shfl_xor(q,o); }
  __shared__ float as[4], aq[4];
  if ((t & 63) == 0){ as[t>>6] = s; aq[t>>6] = q; }
  __syncthreads();
  float S = as[0]+as[1]+as[2]+as[3];
  float Q = aq[0]+aq[1]+aq[2]+aq[3];
  float mu = S*(1.f/8192.f);
  float var = fmaxf(Q*(1.f/8192.f) - mu*mu, 0.f);
  float rstd = rsqrtf(var + 1e-5f);
  float gain = g[c]*rstd;
  float beta = bb[c] - gain*mu;
  float4 v = *(const float4*)(hbuf + ebase + t*4);
  float4 r;
  r.x = lrelu_(gain*v.x + beta);
  r.y = lrelu_(gain*v.y + beta);
  r.z = lrelu_(gain*v.z + beta);
  r.w = lrelu_(gain*v.w + beta);
  *(float4*)(hbuf + ebase + t*4) = r;
}

// ---------------- five 1x1 convs, section-split ----------------
// grid 1536 = sec(3) x b(2) x tile(256 of 16 px); block 256 = 4 waves x 4 px.
__global__ __launch_bounds__(256) void cv1_kernel(
    const float* __restrict__ hbuf, const float* __restrict__ pos,
    const float* __restrict__ kold, const float* __restrict__ vold,
    const float* __restrict__ qwt,
    const float* __restrict__ fkwt, const float* __restrict__ ckwt,
    const float* __restrict__ fvwt, const float* __restrict__ cvwt,
    const float* __restrict__ qbi,  const float* __restrict__ fkb,
    const float* __restrict__ ckb,  const float* __restrict__ fvb,
    const float* __restrict__ cvb,
    unsigned short* __restrict__ qh, unsigned short* __restrict__ ql,
    float* __restrict__ knew, unsigned short* __restrict__ khn, unsigned short* __restrict__ kln,
    float* __restrict__ vnew, unsigned short* __restrict__ vhTn, unsigned short* __restrict__ vlTn)
{
  int t = threadIdx.x;
  int o  = t & 63;
  int wv = t >> 6;                      // 0..3
  int sec  = blockIdx.x >> 9;           // 0,1,2
  int bid  = blockIdx.x & 511;
  int b    = bid >> 8;
  int tile = bid & 255;
  int n0 = tile*16 + wv*4;

  const float* hb = hbuf + b*CHN*NPIX + n0;
  const float* pb = pos + n0;

  auto load4 = [&](const float* p, float* dst){
    float4 a = *(const float4*)p;
    dst[0]=a.x; dst[1]=a.y; dst[2]=a.z; dst[3]=a.w;
  };

  float x[4];
  long obase = (long)(b*CHN+o)*NPIX + n0;
  size_t nbase = ((size_t)b*NPIX + n0)*64 + o;

  if (sec == 0){
    float aq[4];
    float bias = qbi[o];
    #pragma unroll
    for (int j=0;j<4;++j) aq[j]=bias;
    #pragma unroll 4
    for (int i=0;i<64;++i){
      load4(hb + i*NPIX, x);
      float w = qwt[i*64 + o];
      #pragma unroll
      for (int j=0;j<4;++j) aq[j] += w*x[j];
    }
    #pragma unroll 4
    for (int i=0;i<32;++i){
      load4(pb + i*NPIX, x);
      float w = qwt[(64+i)*64 + o];
      #pragma unroll
      for (int j=0;j<4;++j) aq[j] += w*x[j];
    }
    const float QS = 0.125f;            // expf-domain softmax
    #pragma unroll
    for (int j=0;j<4;++j){
      float v = lrelu_(aq[j]) * QS;
      unsigned short hb16 = f2bf(v);
      qh[nbase + (size_t)j*64] = hb16;
      ql[nbase + (size_t)j*64] = f2bf(v - bf2f(hb16));
    }
  } else if (sec == 1){
    const float* kb = kold + b*CHN*NPIX + n0;
    float af[4], ac[4];
    float bf = fkb[o], bc = ckb[o];
    #pragma unroll
    for (int j=0;j<4;++j){ af[j]=bf; ac[j]=bc; }
    #pragma unroll 4
    for (int i=0;i<64;++i){
      load4(hb + i*NPIX, x);
      float wf = fkwt[i*64+o], wc = ckwt[i*64+o];
      #pragma unroll
      for (int j=0;j<4;++j){ af[j] += wf*x[j]; ac[j] += wc*x[j]; }
    }
    #pragma unroll 4
    for (int i=0;i<32;++i){
      load4(pb + i*NPIX, x);
      float wf = fkwt[(64+i)*64+o], wc = ckwt[(64+i)*64+o];
      #pragma unroll
      for (int j=0;j<4;++j){ af[j] += wf*x[j]; ac[j] += wc*x[j]; }
    }
    #pragma unroll 4
    for (int i=0;i<64;++i){
      load4(kb + i*NPIX, x);
      float wf = fkwt[(96+i)*64+o], wc = ckwt[(96+i)*64+o];
      #pragma unroll
      for (int j=0;j<4;++j){ af[j] += wf*x[j]; ac[j] += wc*x[j]; }
    }
    float kv[4];
    load4(kb + o*NPIX, kv);
    #pragma unroll
    for (int j=0;j<4;++j){
      float fk = 1.f/(1.f+__expf(-af[j]));
      float kn = fk*kv[j] + lrelu_(ac[j]);
      knew[obase+j] = kn;
      unsigned short hb16 = f2bf(kn);
      khn[nbase + (size_t)j*64] = hb16;
      kln[nbase + (size_t)j*64] = f2bf(kn - bf2f(hb16));
    }
  } else {
    const float* vb = vold + b*CHN*NPIX + n0;
    float af[4], ac[4];
    float bf = fvb[o], bc = cvb[o];
    #pragma unroll
    for (int j=0;j<4;++j){ af[j]=bf; ac[j]=bc; }
    #pragma unroll 4
    for (int i=0;i<64;++i){
      load4(hb + i*NPIX, x);
      float wf = fvwt[i*64+o], wc = cvwt[i*64+o];
      #pragma unroll
      for (int j=0;j<4;++j){ af[j] += wf*x[j]; ac[j] += wc*x[j]; }
    }
    #pragma unroll 4
    for (int i=0;i<32;++i){
      load4(pb + i*NPIX, x);
      float wf = fvwt[(64+i)*64+o], wc = cvwt[(64+i)*64+o];
      #pragma unroll
      for (int j=0;j<4;++j){ af[j] += wf*x[j]; ac[j] += wc*x[j]; }
    }
    #pragma unroll 4
    for (int i=0;i<64;++i){
      load4(vb + i*NPIX, x);
      float wf = fvwt[(96+i)*64+o], wc = cvwt[(96+i)*64+o];
      #pragma unroll
      for (int j=0;j<4;++j){ af[j] += wf*x[j]; ac[j] += wc*x[j]; }
    }
    float vv[4];
    load4(vb + o*NPIX, vv);
    ushort4v vph, vpl;
    #pragma unroll
    for (int j=0;j<4;++j){
      float fv = 1.f/(1.f+__expf(-af[j]));
      float vn = fv*vv[j] + lrelu_(ac[j]);
      vnew[obase+j] = vn;
      unsigned short hb16 = f2bf(vn);
      vph[j] = hb16;
      vpl[j] = f2bf(vn - bf2f(hb16));
    }
    *(ushort4v*)(vhTn + ((size_t)(b*CHN+o))*NPIX + n0) = vph;
    *(ushort4v*)(vlTn + ((size_t)(b*CHN+o))*NPIX + n0) = vpl;
  }
}

// ---------------- MFMA flash attention (16x16x32, 640 blocks) ----
// XCD-partitioned swizzle: batch 0 -> XCDs 0-3, batch 1 -> XCDs 4-7
// (per-XCD L2 then holds one batch's q+K/V = 3 MB < 4 MB).
__global__ __launch_bounds__(128) void attn_mfma(
    const unsigned short* __restrict__ qhg, const unsigned short* __restrict__ qlg,
    const unsigned short* __restrict__ khg, const unsigned short* __restrict__ klg,
    const unsigned short* __restrict__ vhg, const unsigned short* __restrict__ vlg,
    float* __restrict__ part)
{
  int xcd = blockIdx.x & 7;                  // dispatch round-robins bid%8 -> XCD
  int s   = blockIdx.x >> 3;                 // 0..79
  int b   = xcd >> 2;                        // batch -> XCD half
  int id  = 319 - (s*4 + (xcd & 3));         // longest bands dispatched first
  int pidx = b*320 + id;
  int rem = id, k = 0;
  while (rem >= 32*(k+1)){ rem -= 32*(k+1); ++k; }
  int rt    = 32*k + rem/(k+1);
  int chunk = rem - (rem/(k+1))*(k+1);

  int C0  = chunk << 10;                      // 1024*chunk
  int end = min(C0 + 1024, rt*32 + 32);
  int nt  = (end - C0 + 63) >> 6;

  int t = threadIdx.x;
  int w = t >> 6;
  int l = t & 63;
  int r = l & 15;
  int g = l >> 4;
  int n_g = rt*32 + w*16 + r;                 // this lane's q-row

  __shared__ __align__(16) char KH[8192], KL[8192];
  __shared__ __align__(16) char VH[8192], VL[8192];
  __shared__ __align__(16) char PH[2][2048], PL[2][2048];

  const unsigned short* qhp = qhg + (size_t)b*NPIX*64;
  const unsigned short* qlp = qlg + (size_t)b*NPIX*64;
  const unsigned short* khp = khg + (size_t)b*NPIX*64;
  const unsigned short* klp = klg + (size_t)b*NPIX*64;
  const unsigned short* vhp = vhg + (size_t)b*CHN*NPIX;
  const unsigned short* vlp = vlg + (size_t)b*CHN*NPIX;

  short8 qh0 = *(const short8*)(qhp + (size_t)n_g*64 + 8*g);
  short8 qh1 = *(const short8*)(qhp + (size_t)n_g*64 + 8*g + 32);
  short8 ql0 = *(const short8*)(qlp + (size_t)n_g*64 + 8*g);
  short8 ql1 = *(const short8*)(qlp + (size_t)n_g*64 + 8*g + 32);

  int srow[4], scc8[4], soff[4];
  #pragma unroll
  for (int p=0; p<4; ++p){
    int slot = t + (p<<7);
    int row = slot >> 3, cc = slot & 7;
    srow[p] = row; scc8[p] = cc*8;
    soff[p] = row*128 + ((cc ^ (row & 7)) << 4);
  }

  ushort8 rkh[4], rkl[4], rvh[4], rvl[4];
  auto issue = [&](int m0){
    #pragma unroll
    for (int p=0; p<4; ++p){
      rkh[p] = *(const ushort8*)(khp + (size_t)(m0+srow[p])*64 + scc8[p]);
      rkl[p] = *(const ushort8*)(klp + (size_t)(m0+srow[p])*64 + scc8[p]);
      rvh[p] = *(const ushort8*)(vhp + (size_t)srow[p]*NPIX + m0 + scc8[p]);
      rvl[p] = *(const ushort8*)(vlp + (size_t)srow[p]*NPIX + m0 + scc8[p]);
    }
  };

  f32x4 zero4 = {0.f,0.f,0.f,0.f};
  f32x4 oacc[4];
  #pragma unroll
  for (int vf=0; vf<4; ++vf) oacc[vf] = zero4;
  float m_run = -1e30f, l_run = 0.f;

  int nmax_w = rt*32 + w*16 + 15;

  issue(C0);
  for (int ti=0; ti<nt; ++ti){
    int m0 = C0 + (ti<<6);
    __syncthreads();
    #pragma unroll
    for (int p=0; p<4; ++p){
      *(ushort8*)(KH + soff[p]) = rkh[p];
      *(ushort8*)(KL + soff[p]) = rkl[p];
      *(ushort8*)(VH + soff[p]) = rvh[p];
      *(ushort8*)(VL + soff[p]) = rvl[p];
    }
    __syncthreads();
    if (ti+1 < nt) issue(m0 + 64);

    if (m0 <= nmax_w){
      f32x4 sf[4];
      #pragma unroll
      for (int mf=0; mf<4; ++mf) sf[mf] = zero4;
      #pragma unroll
      for (int kc=0; kc<2; ++kc){
        short8 qfh = kc ? qh1 : qh0;
        short8 qfl = kc ? ql1 : ql0;
        int ch = ((g + 4*kc) ^ (r & 7)) << 4;
        #pragma unroll
        for (int mf=0; mf<4; ++mf){
          int ro = (16*mf + r)*128;
          short8 ah = *(const short8*)(KH + ro + ch);
          short8 al = *(const short8*)(KL + ro + ch);
          sf[mf] = __builtin_amdgcn_mfma_f32_16x16x32_bf16(ah, qfh, sf[mf], 0,0,0);
          sf[mf] = __builtin_amdgcn_mfma_f32_16x16x32_bf16(al, qfh, sf[mf], 0,0,0);
          sf[mf] = __builtin_amdgcn_mfma_f32_16x16x32_bf16(ah, qfl, sf[mf], 0,0,0);
        }
      }
      float pv[16];
      float mx = -1e30f;
      #pragma unroll
      for (int mf=0; mf<4; ++mf){
        #pragma unroll
        for (int q2=0; q2<4; ++q2){
          int mg = m0 + 16*mf + 4*g + q2;
          float s2 = sf[mf][q2];
          s2 = (mg <= n_g) ? s2 : -1e30f;
          pv[mf*4+q2] = s2;
          mx = fmaxf(mx, s2);
        }
      }
      mx = fmaxf(mx, __shfl_xor(mx, 16));
      mx = fmaxf(mx, __shfl_xor(mx, 32));
      float m_new = fmaxf(m_run, mx);
      float alpha = __expf(m_run - m_new);
      float ps = 0.f;
      #pragma unroll
      for (int i=0; i<16; ++i){ pv[i] = __expf(pv[i] - m_new); ps += pv[i]; }
      ps += __shfl_xor(ps, 16);
      ps += __shfl_xor(ps, 32);
      l_run = l_run*alpha + ps;
      m_run = m_new;

      #pragma unroll
      for (int mf=0; mf<4; ++mf){
        unsigned short h_[4], l_[4];
        #pragma unroll
        for (int q2=0; q2<4; ++q2){
          float xv = pv[mf*4+q2];
          h_[q2] = f2bf(xv);
          l_[q2] = f2bf(xv - bf2f(h_[q2]));
        }
        int addr = r*128 + ((((g>>1) + 2*mf) ^ (r & 7)) << 4) + ((g&1)<<3);
        uint2 wh = make_uint2((unsigned)h_[0] | ((unsigned)h_[1]<<16),
                              (unsigned)h_[2] | ((unsigned)h_[3]<<16));
        uint2 wl = make_uint2((unsigned)l_[0] | ((unsigned)l_[1]<<16),
                              (unsigned)l_[2] | ((unsigned)l_[3]<<16));
        *(uint2*)(PH[w] + addr) = wh;
        *(uint2*)(PL[w] + addr) = wl;
      }
      #pragma unroll
      for (int vf=0; vf<4; ++vf) oacc[vf] *= alpha;

      #pragma unroll
      for (int kc=0; kc<2; ++kc){
        int ch = ((g + 4*kc) ^ (r & 7)) << 4;
        short8 pfh = *(const short8*)(PH[w] + r*128 + ch);
        short8 pfl = *(const short8*)(PL[w] + r*128 + ch);
        #pragma unroll
        for (int vf=0; vf<4; ++vf){
          int ro = (16*vf + r)*128;
          short8 ah = *(const short8*)(VH + ro + ch);
          short8 al = *(const short8*)(VL + ro + ch);
          oacc[vf] = __builtin_amdgcn_mfma_f32_16x16x32_bf16(ah, pfh, oacc[vf], 0,0,0);
          oacc[vf] = __builtin_amdgcn_mfma_f32_16x16x32_bf16(al, pfh, oacc[vf], 0,0,0);
          oacc[vf] = __builtin_amdgcn_mfma_f32_16x16x32_bf16(ah, pfl, oacc[vf], 0,0,0);
        }
      }
    }
  }

  float* pacc = part + (size_t)pidx * 2112;
  int nl = w*16 + r;
  #pragma unroll
  for (int vf=0; vf<4; ++vf)
    *(f32x4*)(pacc + nl*64 + 16*vf + 4*g) = oacc[vf];
  if (g == 0){
    pacc[2048 + nl*2]   = m_run;
    pacc[2048 + nl*2+1] = l_run;
  }
}

// ---------------- attention phase 2: combine partials + emit BN partial sums ----
__global__ __launch_bounds__(256) void attn_combine(const float* __restrict__ part,
                                                    float* __restrict__ out1,
                                                    float* __restrict__ psum,
                                                    float* __restrict__ psq){
  int bid = blockIdx.x;               // b*128 + rt
  int b = bid >> 7, rt = bid & 127;
  int k = rt >> 5;
  int nch = k + 1;                    // <= 4
  int base = b*320 + 16*k*(k+1) + (rt - 32*k)*nch;

  int t = threadIdx.x;
  int nl = t & 31, vq = t >> 5;       // 32 rows x 8 vd-octets

  float M = -1e30f;
  #pragma unroll
  for (int c=0; c<4; ++c)
    if (c < nch) M = fmaxf(M, part[(size_t)(base+c)*2112 + 2048 + nl*2]);

  float L = 0.f;
  float val[8];
  #pragma unroll
  for (int jj=0; jj<8; ++jj) val[jj] = 0.f;
  #pragma unroll
  for (int c=0; c<4; ++c){
    if (c < nch){
      const float* pa = part + (size_t)(base+c)*2112;
      float wgt = __expf(pa[2048 + nl*2] - M);
      L += pa[2048 + nl*2 + 1] * wgt;
      #pragma unroll
      for (int jj=0; jj<8; ++jj) val[jj] += wgt * pa[nl*64 + vq*8 + jj];
    }
  }
  float invL = 1.f / L;
  float s[8], q[8];
  #pragma unroll
  for (int jj=0; jj<8; ++jj){
    float v = val[jj]*invL;
    out1[((size_t)b*CHN + vq*8 + jj)*NPIX + rt*32 + nl] = v;
    s[jj] = v; q[jj] = v*v;
  }
  #pragma unroll
  for (int o2=1; o2<32; o2<<=1){
    #pragma unroll
    for (int jj=0; jj<8; ++jj){
      s[jj] += __shfl_xor(s[jj], o2);
      q[jj] += __shfl_xor(q[jj], o2);
    }
  }
  if (nl == 0){
    #pragma unroll
    for (int jj=0; jj<8; ++jj){
      int c = vq*8 + jj;
      psum[c*256 + bid] = s[jj];
      psq [c*256 + bid] = q[jj];
    }
  }
}

// ---------------- final 1x1 conv ----------------
__global__ __launch_bounds__(256) void final_kernel(const float* __restrict__ h,
                                                    const float* __restrict__ ow,
                                                    const float* __restrict__ ob,
                                                    float* __restrict__ out){
  int idx = blockIdx.x*256 + threadIdx.x;     // 819200
  int b  = idx / 409600;
  int r  = idx - b*409600;
  int oc = r >> 12;
  int n  = r & (NPIX-1);
  const float* hp = h + (size_t)b*CHN*NPIX + n;
  const float* wp = ow + oc*64;
  float acc = ob[oc];
  #pragma unroll
  for (int v=0; v<64; ++v) acc += wp[v]*hp[(size_t)v*NPIX];
  out[idx] = acc;
}

extern "C" void kernel_launch(void* const* d_in, const int* in_sizes, int n_in,
                              void* d_out, int out_size, void* d_ws, size_t ws_size,
                              hipStream_t stream){
  const float* x     = (const float*)d_in[0];
  const float* convw = (const float*)d_in[1];
  const float* convb = (const float*)d_in[2];
  const float* bn0g  = (const float*)d_in[3];
  const float* bn0b  = (const float*)d_in[4];
  const float* qw    = (const float*)d_in[5];
  const float* qbias = (const float*)d_in[6];
  const float* fkw   = (const float*)d_in[7];
  const float* fkb   = (const float*)d_in[8];
  const float* ckw   = (const float*)d_in[9];
  const float* ckb   = (const float*)d_in[10];
  const float* fvw   = (const float*)d_in[11];
  const float* fvb   = (const float*)d_in[12];
  const float* cvw   = (const float*)d_in[13];
  const float* cvb   = (const float*)d_in[14];
  const float* bng   = (const float*)d_in[15];
  const float* bnb   = (const float*)d_in[16];
  const float* ow    = (const float*)d_in[17];
  const float* ob    = (const float*)d_in[18];

  const size_t TEN = (size_t)2*CHN*NPIX;   // 524288 elements
  const size_t BFU = TEN/2;                // float-units per bf16 tensor
  float* ws   = (float*)d_ws;
  float* pos  = ws;                 // 131072
  float* h    = pos + 32*NPIX;      // 524288
  // --- contiguous zero region: k0, v0, kh0, kl0, vh0, vl0 (+pad) ---
  float* zbase = h + TEN;
  float* k0   = zbase;                          // TEN
  float* v0   = k0 + TEN;                       // TEN
  unsigned short* kh0 = (unsigned short*)(v0 + TEN);     // BFU f-units
  unsigned short* kl0 = (unsigned short*)(v0 + TEN + BFU);
  unsigned short* vh0 = (unsigned short*)(v0 + TEN + 2*BFU);
  unsigned short* vl0 = (unsigned short*)(v0 + TEN + 3*BFU);
  const size_t ZBYTES = (2*TEN + 4*BFU)*4 + 64;
  float* nz   = v0 + TEN + 4*BFU + 16;
  float* k1   = nz;                 // TEN
  float* v1   = k1 + TEN;           // TEN
  unsigned short* kh1 = (unsigned short*)(v1 + TEN);
  unsigned short* kl1 = (unsigned short*)(v1 + TEN + BFU);
  unsigned short* vh1 = (unsigned short*)(v1 + TEN + 2*BFU);
  unsigned short* vl1 = (unsigned short*)(v1 + TEN + 3*BFU);
  float* stats = v1 + TEN + 4*BFU;  // 128
  float* psum = stats + 128;        // 64*256
  float* psq  = psum + 64*256;      // 64*256
  float* wt   = psq + 64*256;       // 381632
  unsigned short* qh = (unsigned short*)(wt + 381632);
  unsigned short* ql = (unsigned short*)(wt + 381632 + BFU);
  float* part = wt + 381632 + 2*BFU;  // 640 * 2112 floats

  hipMemsetAsync(zbase, 0, ZBYTES, stream);

  poswtr_kernel<<<2003,256,0,stream>>>(qw, fkw, ckw, fvw, cvw, convw, pos, wt);
  conv_in_kernel<<<2048,256,0,stream>>>(x, wt + 376832, convb, h);
  bn_stats_kernel<<<64,1024,0,stream>>>(h, stats);
  bn_apply_kernel<<<512,256,0,stream>>>(h, stats, bn0g, bn0b, h);

  float* kfp[2] = {k0,k1};
  float* vfp[2] = {v0,v1};
  unsigned short* khb[2] = {kh0,kh1};
  unsigned short* klb[2] = {kl0,kl1};
  unsigned short* vhb[2] = {vh0,vh1};
  unsigned short* vlb[2] = {vl0,vl1};
  for (int l=0; l<8; ++l){
    float* kold = kfp[l&1]; float* knew = kfp[(l+1)&1];
    float* vold = vfp[l&1]; float* vnew = vfp[(l+1)&1];
    cv1_kernel<<<1536,256,0,stream>>>(h, pos, kold, vold,
        wt + l*6144,
        wt + 49152 + l*10240,
        wt + 49152 + 81920 + l*10240,
        wt + 49152 + 2*81920 + l*10240,
        wt + 49152 + 3*81920 + l*10240,
        qbias + l*64, fkb + l*64, ckb + l*64, fvb + l*64, cvb + l*64,
        qh, ql,
        knew, khb[(l+1)&1], klb[(l+1)&1],
        vnew, vhb[(l+1)&1], vlb[(l+1)&1]);
    attn_mfma<<<640,128,0,stream>>>(qh, ql, khb[l&1], klb[l&1], vhb[l&1], vlb[l&1], part);
    attn_combine<<<256,256,0,stream>>>(part, h, psum, psq);
    bn_apply2_kernel<<<512,256,0,stream>>>(h, psum, psq, bng + l*64, bnb + l*64);
  }
  final_kernel<<<3200,256,0,stream>>>(h, ow, ob, (float*)d_out);
}